// Round 1
// baseline (1063.687 us; speedup 1.0000x reference)
//
#include <hip/hip_runtime.h>
#include <math.h>

#define NPTS 8192
#define NB   4
#define KNN  16
#define NC   64

// ---------------------------------------------------------------------------
// prep: per-point tables.
//   cand[b][m] = (x, y, z, x^2+y^2+z^2) of xyz_s           (for KNN scoring)
//   F2[b][m][o] = Wf[:,64:128] @ fea_s[:,m]                 (neighbor feat term)
//   Gk[b][m][o] = (Wg[:,4:7] - Wg[:,7:10]) @ xyz_s[:,m]     (neighbor geo term)
//   F1[b][n][o] = Wf[:,0:64]  @ fea[:,n]   + bf             (center feat term)
//   Gc[b][n][o] = (Wg[:,1:4] + Wg[:,7:10]) @ xyz[:,n] + bg  (center geo term)
// ---------------------------------------------------------------------------
__global__ __launch_bounds__(256) void prep_kernel(
    const float* __restrict__ xyz, const float* __restrict__ xyz_s,
    const float* __restrict__ fea, const float* __restrict__ fea_s,
    const float* __restrict__ Wg,  const float* __restrict__ bg,
    const float* __restrict__ Wf,  const float* __restrict__ bf,
    float4* __restrict__ cand, float* __restrict__ Gk, float* __restrict__ F2,
    float* __restrict__ Gc, float* __restrict__ F1)
{
    __shared__ float wt[64 * 64];   // transposed feature weights [c][o]
    __shared__ float gw[3 * 64];    // geo weights [d][o]
    int tid = threadIdx.x;
    int g   = blockIdx.x * 256 + tid;
    int b   = g >> 13, m = g & (NPTS - 1);

    // ---------------- phase A: source-point tables ----------------
    for (int i = tid; i < 4096; i += 256) {
        int o = i >> 6, c = i & 63;
        wt[c * 64 + o] = Wf[o * 128 + 64 + c];
    }
    if (tid < 192) {
        int d = tid >> 6, o = tid & 63;
        gw[d * 64 + o] = Wg[o * 10 + 4 + d] - Wg[o * 10 + 7 + d];
    }
    __syncthreads();
    {
        float x = xyz_s[(b * 3 + 0) * NPTS + m];
        float y = xyz_s[(b * 3 + 1) * NPTS + m];
        float z = xyz_s[(b * 3 + 2) * NPTS + m];
        cand[b * NPTS + m] = make_float4(x, y, z, x * x + y * y + z * z);
        float acc[NC];
        #pragma unroll
        for (int o = 0; o < NC; o++) acc[o] = 0.f;
        for (int c = 0; c < NC; c++) {
            float v = fea_s[(size_t)(b * NC + c) * NPTS + m];
            const float4* w4 = (const float4*)&wt[c * 64];
            #pragma unroll
            for (int o4 = 0; o4 < 16; o4++) {
                float4 w = w4[o4];
                acc[o4*4+0] = fmaf(w.x, v, acc[o4*4+0]);
                acc[o4*4+1] = fmaf(w.y, v, acc[o4*4+1]);
                acc[o4*4+2] = fmaf(w.z, v, acc[o4*4+2]);
                acc[o4*4+3] = fmaf(w.w, v, acc[o4*4+3]);
            }
        }
        size_t base = (size_t)(b * NPTS + m) * NC;
        #pragma unroll
        for (int o = 0; o < NC; o++) F2[base + o] = acc[o];
        #pragma unroll
        for (int o = 0; o < NC; o++)
            Gk[base + o] = fmaf(gw[o], x, fmaf(gw[64 + o], y, gw[128 + o] * z));
    }
    __syncthreads();
    // ---------------- phase B: center-point tables ----------------
    for (int i = tid; i < 4096; i += 256) {
        int o = i >> 6, c = i & 63;
        wt[c * 64 + o] = Wf[o * 128 + c];
    }
    if (tid < 192) {
        int d = tid >> 6, o = tid & 63;
        gw[d * 64 + o] = Wg[o * 10 + 1 + d] + Wg[o * 10 + 7 + d];
    }
    __syncthreads();
    {
        float x = xyz[(b * 3 + 0) * NPTS + m];
        float y = xyz[(b * 3 + 1) * NPTS + m];
        float z = xyz[(b * 3 + 2) * NPTS + m];
        float acc[NC];
        #pragma unroll
        for (int o = 0; o < NC; o++) acc[o] = 0.f;
        for (int c = 0; c < NC; c++) {
            float v = fea[(size_t)(b * NC + c) * NPTS + m];
            const float4* w4 = (const float4*)&wt[c * 64];
            #pragma unroll
            for (int o4 = 0; o4 < 16; o4++) {
                float4 w = w4[o4];
                acc[o4*4+0] = fmaf(w.x, v, acc[o4*4+0]);
                acc[o4*4+1] = fmaf(w.y, v, acc[o4*4+1]);
                acc[o4*4+2] = fmaf(w.z, v, acc[o4*4+2]);
                acc[o4*4+3] = fmaf(w.w, v, acc[o4*4+3]);
            }
        }
        size_t base = (size_t)(b * NPTS + m) * NC;
        #pragma unroll
        for (int o = 0; o < NC; o++) F1[base + o] = acc[o] + bf[o];
        #pragma unroll
        for (int o = 0; o < NC; o++)
            Gc[base + o] = fmaf(gw[o], x, fmaf(gw[64 + o], y, gw[128 + o] * z)) + bg[o];
    }
}

// ---------------------------------------------------------------------------
// knn: thread per query. score = 2*<a,b> - |b|^2  (rank-equivalent to ref's
// 2*inner - a2 - b2). Keep 16 largest in an ascending register list.
// ---------------------------------------------------------------------------
__global__ __launch_bounds__(64) void knn_kernel(
    const float4* __restrict__ cand, const float* __restrict__ xyz,
    int* __restrict__ idxout)
{
    int tid = threadIdx.x;
    int g = blockIdx.x * 64 + tid;
    int b = g >> 13, n = g & (NPTS - 1);
    float qx = xyz[(b * 3 + 0) * NPTS + n];
    float qy = xyz[(b * 3 + 1) * NPTS + n];
    float qz = xyz[(b * 3 + 2) * NPTS + n];
    float ax = 2.f * qx, ay = 2.f * qy, az = 2.f * qz;

    float s[KNN];
    int   si[KNN];
    #pragma unroll
    for (int j = 0; j < KNN; j++) { s[j] = -3.0e38f; si[j] = 0; }

    __shared__ float4 tile[256];
    const float4* cb = cand + b * NPTS;

    for (int t0 = 0; t0 < NPTS; t0 += 256) {
        __syncthreads();
        #pragma unroll
        for (int i = 0; i < 4; i++) tile[tid + i * 64] = cb[t0 + tid + i * 64];
        __syncthreads();
        #pragma unroll 4
        for (int i = 0; i < 256; i++) {
            float4 c = tile[i];
            float sc = fmaf(ax, c.x, fmaf(ay, c.y, fmaf(az, c.z, -c.w)));
            if (sc > s[0]) {
                int mi = t0 + i;
                bool cj = true;
                #pragma unroll
                for (int j = 0; j < KNN; j++) {
                    bool cn = (j < KNN - 1) ? (sc > s[j + 1]) : false;
                    float fv = cj ? sc : s[j];
                    int   iv = cj ? mi : si[j];
                    s[j]  = cn ? s[j + 1]  : fv;
                    si[j] = cn ? si[j + 1] : iv;
                    cj = cn;
                }
            }
        }
    }
    int* op = idxout + (size_t)(b * NPTS + n) * KNN;
    #pragma unroll
    for (int j = 0; j < KNN; j++) op[j] = si[j];
}

// ---------------------------------------------------------------------------
// fuse: out[b][o][n] = max_k relu(Gc+Gk+wd*d) * relu(F1+F2)
// block = 256 threads = 4 waves; 16 queries per block; LDS transpose for
// coalesced output stores.
// ---------------------------------------------------------------------------
__global__ __launch_bounds__(256) void fuse_kernel(
    const float* __restrict__ xyz, const float* __restrict__ Wg,
    const float4* __restrict__ cand, const float* __restrict__ Gk,
    const float* __restrict__ F2, const float* __restrict__ Gc,
    const float* __restrict__ F1, const int* __restrict__ idxb,
    float* __restrict__ out)
{
    __shared__ float tile[16 * 65];
    int tid = threadIdx.x;
    int o = tid & 63, w = tid >> 6;
    int b = blockIdx.x >> 9;
    int nt = (blockIdx.x & 511) << 4;
    float wd = Wg[o * 10];

    for (int i = 0; i < 4; i++) {
        int q = nt + w * 4 + i;
        size_t qb = (size_t)(b * NPTS + q);
        float qx = xyz[(b * 3 + 0) * NPTS + q];
        float qy = xyz[(b * 3 + 1) * NPTS + q];
        float qz = xyz[(b * 3 + 2) * NPTS + q];
        float gcv = Gc[qb * NC + o];
        float f1v = F1[qb * NC + o];
        const int* ip = idxb + qb * KNN;
        float r = 0.f;
        #pragma unroll 4
        for (int kk = 0; kk < KNN; kk++) {
            int mi = ip[kk];
            float4 c = cand[b * NPTS + mi];
            float dx = qx - c.x, dy = qy - c.y, dz = qz - c.z;
            float d = sqrtf(fmaf(dx, dx, fmaf(dy, dy, dz * dz)));
            size_t mb = (size_t)(b * NPTS + mi) * NC;
            float gkv = Gk[mb + o], f2v = F2[mb + o];
            float gpre = gcv + fmaf(wd, d, gkv);
            float fpre = f1v + f2v;
            r = fmaxf(r, fmaxf(gpre, 0.f) * fmaxf(fpre, 0.f));
        }
        tile[(w * 4 + i) * 65 + o] = r;
    }
    __syncthreads();
    int row = tid >> 2, cg = (tid & 3) * 4;
    float* orow = out + (size_t)(b * NC + row) * NPTS + nt + cg;
    #pragma unroll
    for (int j = 0; j < 4; j++) orow[j] = tile[(cg + j) * 65 + row];
}

extern "C" void kernel_launch(void* const* d_in, const int* in_sizes, int n_in,
                              void* d_out, int out_size, void* d_ws, size_t ws_size,
                              hipStream_t stream) {
    const float* xyz   = (const float*)d_in[0];
    const float* xyz_s = (const float*)d_in[1];
    const float* fea   = (const float*)d_in[2];
    const float* fea_s = (const float*)d_in[3];
    const float* Wg    = (const float*)d_in[4];
    const float* bg    = (const float*)d_in[5];
    const float* Wf    = (const float*)d_in[6];
    const float* bf    = (const float*)d_in[7];
    float* out = (float*)d_out;

    float* ws = (float*)d_ws;
    float4* cand = (float4*)ws;
    float* Gk = ws + (size_t)NB * NPTS * 4;
    float* F2 = Gk + (size_t)NB * NPTS * NC;
    float* Gc = F2 + (size_t)NB * NPTS * NC;
    float* F1 = Gc + (size_t)NB * NPTS * NC;
    int* idxb = (int*)(F1 + (size_t)NB * NPTS * NC);

    prep_kernel<<<NB * NPTS / 256, 256, 0, stream>>>(
        xyz, xyz_s, fea, fea_s, Wg, bg, Wf, bf, cand, Gk, F2, Gc, F1);
    knn_kernel<<<NB * NPTS / 64, 64, 0, stream>>>(cand, xyz, idxb);
    fuse_kernel<<<NB * (NPTS / 16), 256, 0, stream>>>(
        xyz, Wg, cand, Gk, F2, Gc, F1, idxb, out);
}

// Round 2
// 331.643 us; speedup vs baseline: 3.2073x; 3.2073x over previous
//
#include <hip/hip_runtime.h>
#include <math.h>

#define NPTS 8192
#define NB   4
#define KNN  16
#define NC   64
#define CAP  448

// ---------------------------------------------------------------------------
// prep (2 phases as separate blocks):
//  phase 0 (source pts): cand[b][m]=(x,y,z,|p|^2); GF[b][m][o]=(Gk,F2)
//  phase 1 (center pts): CF[b][n][o]=(Gc+bg, F1+bf)
//  Gk = (Wg[:,4:7]-Wg[:,7:10])@xyz_s ; F2 = Wf[:,64:128]@fea_s
//  Gc = (Wg[:,1:4]+Wg[:,7:10])@xyz   ; F1 = Wf[:,0:64]@fea
// ---------------------------------------------------------------------------
__global__ __launch_bounds__(256) void prep_kernel(
    const float* __restrict__ xyz, const float* __restrict__ xyz_s,
    const float* __restrict__ fea, const float* __restrict__ fea_s,
    const float* __restrict__ Wg,  const float* __restrict__ bg,
    const float* __restrict__ Wf,  const float* __restrict__ bf,
    float4* __restrict__ cand, float2* __restrict__ GF, float2* __restrict__ CF)
{
    __shared__ float wt[64 * 64];   // [c][o]
    __shared__ float gw[3 * 64];    // [d][o]
    __shared__ float bias2[2 * 64]; // [g|f][o]
    int tid   = threadIdx.x;
    int phase = blockIdx.x & 1;
    int g     = (blockIdx.x >> 1) * 256 + tid;
    int b     = g >> 13, m = g & (NPTS - 1);

    for (int i = tid; i < 4096; i += 256) {
        int o = i >> 6, c = i & 63;
        wt[c * 64 + o] = Wf[o * 128 + (phase ? c : 64 + c)];
    }
    if (tid < 192) {
        int d = tid >> 6, o = tid & 63;
        gw[d * 64 + o] = phase ? (Wg[o * 10 + 1 + d] + Wg[o * 10 + 7 + d])
                               : (Wg[o * 10 + 4 + d] - Wg[o * 10 + 7 + d]);
    }
    if (tid < 64) {
        bias2[tid]      = phase ? bg[tid] : 0.f;
        bias2[64 + tid] = phase ? bf[tid] : 0.f;
    }
    __syncthreads();

    const float* P = phase ? xyz : xyz_s;
    const float* F = phase ? fea : fea_s;
    float x = P[(b * 3 + 0) * NPTS + m];
    float y = P[(b * 3 + 1) * NPTS + m];
    float z = P[(b * 3 + 2) * NPTS + m];
    if (!phase) cand[b * NPTS + m] = make_float4(x, y, z, x * x + y * y + z * z);

    float acc[NC];
    #pragma unroll
    for (int o = 0; o < NC; o++) acc[o] = 0.f;
    for (int c = 0; c < NC; c++) {
        float v = F[(size_t)(b * NC + c) * NPTS + m];
        const float4* w4 = (const float4*)&wt[c * 64];
        #pragma unroll
        for (int o4 = 0; o4 < 16; o4++) {
            float4 w = w4[o4];
            acc[o4*4+0] = fmaf(w.x, v, acc[o4*4+0]);
            acc[o4*4+1] = fmaf(w.y, v, acc[o4*4+1]);
            acc[o4*4+2] = fmaf(w.z, v, acc[o4*4+2]);
            acc[o4*4+3] = fmaf(w.w, v, acc[o4*4+3]);
        }
    }
    float2* O = (phase ? CF : GF) + ((size_t)(b * NPTS + m)) * NC;
    #pragma unroll
    for (int o = 0; o < NC; o++) {
        float geo = fmaf(gw[o], x, fmaf(gw[64 + o], y, gw[128 + o] * z));
        O[o] = make_float2(geo + bias2[o], acc[o] + bias2[64 + o]);
    }
}

// ---------------------------------------------------------------------------
// knn: wave-per-query threshold select.
//  A: per-lane max over 32-sample slice -> bitonic -> tau0 = 16th of 64 maxima
//     (valid lower bound on true 16th-best: 16 distinct witnesses >= tau0)
//  B: full scan, push (score,idx) with sc >= tau0 into per-query LDS buffer
//  C: 16 rounds of wave argmax over survivors (u64 = sortable_score|8191-idx,
//     tie -> smaller idx, matching jax top_k)
// ---------------------------------------------------------------------------
__global__ __launch_bounds__(512) void knn_kernel(
    const float4* __restrict__ cand, const float* __restrict__ xyz,
    int* __restrict__ idxout)
{
    __shared__ float4 tile[2048];
    __shared__ unsigned long long sel[8][CAP];
    __shared__ int cnt[8];

    int tid = threadIdx.x;
    int lane = tid & 63, w = tid >> 6;
    int b = blockIdx.x >> 10;                      // 1024 blocks per batch
    int q = ((blockIdx.x & 1023) << 3) + w;
    const float4* cb = cand + b * NPTS;

    float qx = xyz[(b * 3 + 0) * NPTS + q];
    float qy = xyz[(b * 3 + 1) * NPTS + q];
    float qz = xyz[(b * 3 + 2) * NPTS + q];
    float ax = 2.f * qx, ay = 2.f * qy, az = 2.f * qz;

    // ---- phase A: sampled per-lane maxima ----
    float m = -3.0e38f;
    for (int t = 0; t < 4; t++) {
        __syncthreads();
        #pragma unroll
        for (int i = tid; i < 2048; i += 512) tile[i] = cb[t * 2048 + i];
        __syncthreads();
        #pragma unroll
        for (int j = 0; j < 8; j++) {
            float4 c = tile[lane + (j << 8)];
            float sc = fmaf(ax, c.x, fmaf(ay, c.y, fmaf(az, c.z, -c.w)));
            m = fmaxf(m, sc);
        }
    }
    // bitonic sort ascending across 64 lanes; lane 48 holds 16th largest
    #pragma unroll
    for (int k = 2; k <= 64; k <<= 1) {
        #pragma unroll
        for (int j = k >> 1; j > 0; j >>= 1) {
            float o = __shfl_xor(m, j);
            bool up = ((lane & k) == 0);
            bool lower = ((lane & j) == 0);
            m = (up == lower) ? fminf(m, o) : fmaxf(m, o);
        }
    }
    float tau = __shfl(m, 48);
    if (lane == 0) cnt[w] = 0;

    // ---- phase B: filter-scan all candidates ----
    for (int t = 0; t < 4; t++) {
        __syncthreads();
        #pragma unroll
        for (int i = tid; i < 2048; i += 512) tile[i] = cb[t * 2048 + i];
        __syncthreads();
        #pragma unroll 4
        for (int j = 0; j < 32; j++) {
            int i = lane + (j << 6);
            float4 c = tile[i];
            float sc = fmaf(ax, c.x, fmaf(ay, c.y, fmaf(az, c.z, -c.w)));
            if (sc >= tau) {
                unsigned u = __float_as_uint(sc);
                u ^= (unsigned)((int)u >> 31) | 0x80000000u;
                int pos = atomicAdd(&cnt[w], 1);
                if (pos < CAP)
                    sel[w][pos] = ((unsigned long long)u << 32) |
                                  (unsigned)(8191 - (t * 2048 + i));
            }
        }
    }
    __syncthreads();

    // ---- phase C: 16 rounds of wave argmax ----
    int C = min(cnt[w], CAP);
    int keep = 0;
    for (int r = 0; r < KNN; r++) {
        unsigned long long lbest = 0ull;
        int bpos = -1;
        for (int e = lane; e < C; e += 64) {
            unsigned long long v = sel[w][e];
            if (v > lbest) { lbest = v; bpos = e; }
        }
        unsigned long long gbest = lbest;
        #pragma unroll
        for (int off = 1; off < 64; off <<= 1) {
            unsigned long long o = __shfl_xor(gbest, off);
            if (o > gbest) gbest = o;
        }
        if (lbest == gbest && bpos >= 0) sel[w][bpos] = 0ull;  // unique winner
        if (lane == r) keep = (int)(8191u - (unsigned)(gbest & 0xFFFFFFFFu));
    }
    if (lane < KNN)
        idxout[(((size_t)(b * NPTS + q)) << 4) + lane] = keep;
}

// ---------------------------------------------------------------------------
// fuse: out[b][o][n] = max_k relu(CF.x + wd*d + GF.x) * relu(CF.y + GF.y)
// ---------------------------------------------------------------------------
__global__ __launch_bounds__(256) void fuse_kernel(
    const float* __restrict__ xyz, const float* __restrict__ Wg,
    const float4* __restrict__ cand, const float2* __restrict__ GF,
    const float2* __restrict__ CF, const int* __restrict__ idxb,
    float* __restrict__ out)
{
    __shared__ float tile[16 * 65];
    int tid = threadIdx.x;
    int o = tid & 63, w = tid >> 6;
    int b = blockIdx.x >> 9;
    int nt = (blockIdx.x & 511) << 4;
    float wd = Wg[o * 10];

    for (int i = 0; i < 4; i++) {
        int q = nt + w * 4 + i;
        size_t qb = (size_t)(b * NPTS + q);
        float qx = xyz[(b * 3 + 0) * NPTS + q];
        float qy = xyz[(b * 3 + 1) * NPTS + q];
        float qz = xyz[(b * 3 + 2) * NPTS + q];
        float2 cf = CF[qb * NC + o];
        const int* ip = idxb + qb * KNN;
        float r = 0.f;
        #pragma unroll 4
        for (int kk = 0; kk < KNN; kk++) {
            int mi = ip[kk];
            float4 c = cand[b * NPTS + mi];
            float dx = qx - c.x, dy = qy - c.y, dz = qz - c.z;
            float d = sqrtf(fmaf(dx, dx, fmaf(dy, dy, dz * dz)));
            float2 gf = GF[((size_t)(b * NPTS + mi)) * NC + o];
            float gpre = cf.x + fmaf(wd, d, gf.x);
            float fpre = cf.y + gf.y;
            r = fmaxf(r, fmaxf(gpre, 0.f) * fmaxf(fpre, 0.f));
        }
        tile[(w * 4 + i) * 65 + o] = r;
    }
    __syncthreads();
    int row = tid >> 2, cg = (tid & 3) * 4;
    float* orow = out + (size_t)(b * NC + row) * NPTS + nt + cg;
    #pragma unroll
    for (int j = 0; j < 4; j++) orow[j] = tile[(cg + j) * 65 + row];
}

extern "C" void kernel_launch(void* const* d_in, const int* in_sizes, int n_in,
                              void* d_out, int out_size, void* d_ws, size_t ws_size,
                              hipStream_t stream) {
    const float* xyz   = (const float*)d_in[0];
    const float* xyz_s = (const float*)d_in[1];
    const float* fea   = (const float*)d_in[2];
    const float* fea_s = (const float*)d_in[3];
    const float* Wg    = (const float*)d_in[4];
    const float* bg    = (const float*)d_in[5];
    const float* Wf    = (const float*)d_in[6];
    const float* bf    = (const float*)d_in[7];
    float* out = (float*)d_out;

    float* ws = (float*)d_ws;
    float4* cand = (float4*)ws;                                    // 512 KB
    float2* GF = (float2*)(ws + (size_t)NB * NPTS * 4);            // 16.8 MB
    float2* CF = GF + (size_t)NB * NPTS * NC;                      // 16.8 MB
    int* idxb  = (int*)(CF + (size_t)NB * NPTS * NC);              // 2 MB

    prep_kernel<<<(NB * NPTS / 256) * 2, 256, 0, stream>>>(
        xyz, xyz_s, fea, fea_s, Wg, bg, Wf, bf, cand, GF, CF);
    knn_kernel<<<NB * NPTS / 8, 512, 0, stream>>>(cand, xyz, idxb);
    fuse_kernel<<<NB * (NPTS / 16), 256, 0, stream>>>(
        xyz, Wg, cand, GF, CF, idxb, out);
}